// Round 1
// baseline (622.604 us; speedup 1.0000x reference)
//
#include <hip/hip_runtime.h>

#define NCLS 100
#define EPS 1e-7f

// d_ws layout: counts[0..99]=pred_count, [100..199]=true_count, [200..299]=tp
__global__ void zero_counts_kernel(unsigned int* __restrict__ counts) {
    int i = threadIdx.x;
    if (i < 3 * NCLS) counts[i] = 0u;
}

__global__ __launch_bounds__(256) void hist_kernel(
        const float* __restrict__ logits,
        const int* __restrict__ labels,
        unsigned int* __restrict__ counts,
        int N) {
    __shared__ unsigned int s_pred[NCLS];
    __shared__ unsigned int s_true[NCLS];
    __shared__ unsigned int s_tp[NCLS];
    for (int i = threadIdx.x; i < NCLS; i += blockDim.x) {
        s_pred[i] = 0u; s_true[i] = 0u; s_tp[i] = 0u;
    }
    __syncthreads();

    const int stride = gridDim.x * blockDim.x;
    for (int row = blockIdx.x * blockDim.x + threadIdx.x; row < N; row += stride) {
        const float4* p = (const float4*)(logits + (size_t)row * NCLS);
        float best = -INFINITY;
        int bi = 0;
        // first-max semantics (match jnp.argmax): strict > in index order
        #pragma unroll
        for (int j = 0; j < NCLS / 4; ++j) {
            float4 v = p[j];
            int c = j * 4;
            if (v.x > best) { best = v.x; bi = c;     }
            if (v.y > best) { best = v.y; bi = c + 1; }
            if (v.z > best) { best = v.z; bi = c + 2; }
            if (v.w > best) { best = v.w; bi = c + 3; }
        }
        int lab = labels[row];
        atomicAdd(&s_pred[bi], 1u);
        atomicAdd(&s_true[lab], 1u);
        if (bi == lab) atomicAdd(&s_tp[lab], 1u);
    }

    __syncthreads();
    for (int i = threadIdx.x; i < NCLS; i += blockDim.x) {
        unsigned int v;
        if ((v = s_pred[i]) != 0u) atomicAdd(&counts[i], v);
        if ((v = s_true[i]) != 0u) atomicAdd(&counts[NCLS + i], v);
        if ((v = s_tp[i])   != 0u) atomicAdd(&counts[2 * NCLS + i], v);
    }
}

__global__ void finalize_kernel(const unsigned int* __restrict__ counts,
                                float* __restrict__ out) {
    __shared__ float s_f1[NCLS];
    int c = threadIdx.x;
    if (c < NCLS) {
        float tp    = (float)counts[2 * NCLS + c];
        float predc = (float)counts[c];            // tp + fp
        float truec = (float)counts[NCLS + c];     // tp + fn
        float fp = predc - tp;
        float fn = truec - tp;
        float precision = tp / (tp + fp + EPS);
        float recall    = tp / (tp + fn + EPS);
        float f1 = 2.0f * precision * recall / (precision + recall + EPS);
        s_f1[c] = f1;
    }
    __syncthreads();
    if (c == 0) {
        float sum = 0.0f;
        for (int i = 0; i < NCLS; ++i) sum += s_f1[i];
        out[0] = sum / (float)NCLS;
    }
}

extern "C" void kernel_launch(void* const* d_in, const int* in_sizes, int n_in,
                              void* d_out, int out_size, void* d_ws, size_t ws_size,
                              hipStream_t stream) {
    const float* logits = (const float*)d_in[0];
    const int*   labels = (const int*)d_in[1];
    float* out = (float*)d_out;
    unsigned int* counts = (unsigned int*)d_ws;  // 300 u32 = 1200 B scratch

    const int N = in_sizes[1];  // 1,000,000 rows

    zero_counts_kernel<<<1, 320, 0, stream>>>(counts);

    const int block = 256;
    const int grid  = 2048;  // 8 blocks/CU, grid-stride over rows
    hist_kernel<<<grid, block, 0, stream>>>(logits, labels, counts, N);

    finalize_kernel<<<1, 128, 0, stream>>>(counts, out);
}

// Round 2
// 532.391 us; speedup vs baseline: 1.1694x; 1.1694x over previous
//
#include <hip/hip_runtime.h>

#define NCLS 100
#define EPS 1e-7f

// d_ws layout: counts[0..99]=pred_count, [100..199]=true_count, [200..299]=tp
__global__ void zero_counts_kernel(unsigned int* __restrict__ counts) {
    int i = threadIdx.x;
    if (i < 3 * NCLS) counts[i] = 0u;
}

__global__ __launch_bounds__(256) void hist_kernel(
        const float* __restrict__ logits,
        const int* __restrict__ labels,
        unsigned int* __restrict__ counts,
        int N) {
    __shared__ unsigned int s_pred[NCLS];
    __shared__ unsigned int s_true[NCLS];
    __shared__ unsigned int s_tp[NCLS];
    for (int i = threadIdx.x; i < NCLS; i += blockDim.x) {
        s_pred[i] = 0u; s_true[i] = 0u; s_tp[i] = 0u;
    }
    __syncthreads();

    const int tid    = blockIdx.x * blockDim.x + threadIdx.x;
    const int q      = tid & 3;        // lane within quad
    const int quad   = tid >> 2;       // global quad id = row id
    const int nquads = (gridDim.x * blockDim.x) >> 2;

    for (int row = quad; row < N; row += nquads) {
        const float4* p = (const float4*)(logits + (size_t)row * NCLS);

        // Lane q loads float4 indices j = 4k+q (k=0..5); quad covers j=0..23
        // contiguously -> 64B segments fully consumed per instruction.
        float4 v[7];
        #pragma unroll
        for (int k = 0; k < 6; ++k) v[k] = p[4 * k + q];
        if (q == 0) v[6] = p[24];      // remainder: columns 96..99

        float best = -INFINITY;
        int bidx = 0;
        #pragma unroll
        for (int k = 0; k < 6; ++k) {
            const int c = (4 * k + q) * 4;
            float4 w = v[k];
            if (w.x > best) { best = w.x; bidx = c;     }
            if (w.y > best) { best = w.y; bidx = c + 1; }
            if (w.z > best) { best = w.z; bidx = c + 2; }
            if (w.w > best) { best = w.w; bidx = c + 3; }
        }
        if (q == 0) {
            float4 w = v[6];
            if (w.x > best) { best = w.x; bidx = 96; }
            if (w.y > best) { best = w.y; bidx = 97; }
            if (w.z > best) { best = w.z; bidx = 98; }
            if (w.w > best) { best = w.w; bidx = 99; }
        }

        // Quad-wide argmax: greater value wins; tie -> lower column index
        // (preserves jnp.argmax first-max semantics).
        #pragma unroll
        for (int m = 1; m <= 2; m <<= 1) {
            float ob = __shfl_xor(best, m, 64);
            int   oi = __shfl_xor(bidx, m, 64);
            if (ob > best || (ob == best && oi < bidx)) { best = ob; bidx = oi; }
        }

        if (q == 0) {
            int lab = labels[row];
            atomicAdd(&s_pred[bidx], 1u);
            atomicAdd(&s_true[lab], 1u);
            if (bidx == lab) atomicAdd(&s_tp[lab], 1u);
        }
    }

    __syncthreads();
    for (int i = threadIdx.x; i < NCLS; i += blockDim.x) {
        unsigned int v;
        if ((v = s_pred[i]) != 0u) atomicAdd(&counts[i], v);
        if ((v = s_true[i]) != 0u) atomicAdd(&counts[NCLS + i], v);
        if ((v = s_tp[i])   != 0u) atomicAdd(&counts[2 * NCLS + i], v);
    }
}

__global__ void finalize_kernel(const unsigned int* __restrict__ counts,
                                float* __restrict__ out) {
    __shared__ float s_f1[NCLS];
    int c = threadIdx.x;
    if (c < NCLS) {
        float tp    = (float)counts[2 * NCLS + c];
        float predc = (float)counts[c];            // tp + fp
        float truec = (float)counts[NCLS + c];     // tp + fn
        float fp = predc - tp;
        float fn = truec - tp;
        float precision = tp / (tp + fp + EPS);
        float recall    = tp / (tp + fn + EPS);
        float f1 = 2.0f * precision * recall / (precision + recall + EPS);
        s_f1[c] = f1;
    }
    __syncthreads();
    if (c == 0) {
        float sum = 0.0f;
        for (int i = 0; i < NCLS; ++i) sum += s_f1[i];
        out[0] = sum / (float)NCLS;
    }
}

extern "C" void kernel_launch(void* const* d_in, const int* in_sizes, int n_in,
                              void* d_out, int out_size, void* d_ws, size_t ws_size,
                              hipStream_t stream) {
    const float* logits = (const float*)d_in[0];
    const int*   labels = (const int*)d_in[1];
    float* out = (float*)d_out;
    unsigned int* counts = (unsigned int*)d_ws;  // 300 u32 = 1200 B scratch

    const int N = in_sizes[1];  // 1,000,000 rows

    zero_counts_kernel<<<1, 320, 0, stream>>>(counts);

    const int block = 256;
    const int grid  = 2048;  // 8 blocks/CU, grid-stride over row quads
    hist_kernel<<<grid, block, 0, stream>>>(logits, labels, counts, N);

    finalize_kernel<<<1, 128, 0, stream>>>(counts, out);
}